// Round 1
// baseline (704.103 us; speedup 1.0000x reference)
//
#include <hip/hip_runtime.h>
#include <hip/hip_bf16.h>
#include <math.h>

// ---------------------------------------------------------------------------
// Hybrid_QuanvModel: conv1+tanh -> maxpool4s2*pi/2 -> quanv(4qubit)+relu ->
// conv2+relu -> maxpool4s1 -> conv3+relu -> maxpool2s1 -> conv4(s2)+relu ->
// fc1..fc3 (+relu) -> fc4 + log_softmax.  B=256.
// ---------------------------------------------------------------------------

__device__ __forceinline__ float2 cmul(float2 a, float2 b) {
    return make_float2(a.x * b.x - a.y * b.y, a.x * b.y + a.y * b.x);
}
__device__ __forceinline__ float2 cfma(float2 a, float2 b, float2 acc) {
    acc.x += a.x * b.x - a.y * b.y;
    acc.y += a.x * b.y + a.y * b.x;
    return acc;
}

// ---------------------------------------------------------------------------
// Build V[s][t] = U3[s][t] * (-i)^popcount(t), U3 = (L3 L2 L1)^3 (16x16).
// One block, 256 threads (thread = one matrix element).
// ---------------------------------------------------------------------------
__global__ __launch_bounds__(256) void k_build_V(const float* __restrict__ qw,
                                                 float2* __restrict__ Vout) {
    __shared__ float2 rot[3][4][2][2];
    __shared__ float2 L[16][16];
    __shared__ float2 U[16][16];
    __shared__ float2 T[16][16];

    int tid = threadIdx.x;
    if (tid < 12) {
        int l = tid >> 2, q = tid & 3;
        float phi = qw[(l * 4 + q) * 3 + 0];
        float th  = qw[(l * 4 + q) * 3 + 1];
        float om  = qw[(l * 4 + q) * 3 + 2];
        float c, s;
        sincosf(0.5f * th, &s, &c);
        float sa, ca, sb, cb;
        sincosf(0.5f * (phi + om), &sa, &ca);
        sincosf(0.5f * (phi - om), &sb, &cb);
        rot[l][q][0][0] = make_float2( ca * c, -sa * c);   // e^{-i(phi+om)/2} c
        rot[l][q][0][1] = make_float2(-cb * s, -sb * s);   // -e^{+i(phi-om)/2} s
        rot[l][q][1][0] = make_float2( cb * s, -sb * s);   // e^{-i(phi-om)/2} s
        rot[l][q][1][1] = make_float2( ca * c,  sa * c);   // e^{+i(phi+om)/2} c
    }
    int s = tid >> 4, t = tid & 15;
    U[s][t] = make_float2((s == t) ? 1.f : 0.f, 0.f);
    __syncthreads();

    for (int l = 0; l < 3; ++l) {
        int r = l + 1;
        // row source: apply CNOT perms p3,p2,p1,p0 (each an involution)
        int ss = s;
        for (int i = 3; i >= 0; --i) {
            int c_ = i, t_ = (i + r) & 3;
            if ((ss >> (3 - c_)) & 1) ss ^= 1 << (3 - t_);
        }
        float2 v = make_float2(1.f, 0.f);
        #pragma unroll
        for (int q = 0; q < 4; ++q) {
            int bs = (ss >> (3 - q)) & 1;
            int bt = (t  >> (3 - q)) & 1;
            v = cmul(v, rot[l][q][bs][bt]);
        }
        L[s][t] = v;
        __syncthreads();
        float2 acc = make_float2(0.f, 0.f);
        #pragma unroll
        for (int k = 0; k < 16; ++k) acc = cfma(L[s][k], U[k][t], acc);
        T[s][t] = acc;
        __syncthreads();
        U[s][t] = T[s][t];
        __syncthreads();
    }
    // U^3
    float2 acc = make_float2(0.f, 0.f);
    #pragma unroll
    for (int k = 0; k < 16; ++k) acc = cfma(U[s][k], U[k][t], acc);
    T[s][t] = acc;              // U^2
    __syncthreads();
    acc = make_float2(0.f, 0.f);
    #pragma unroll
    for (int k = 0; k < 16; ++k) acc = cfma(T[s][k], U[k][t], acc);
    // multiply by (-i)^popcount(t)
    int pc = __popc(t) & 3;
    float2 v;
    if      (pc == 0) v = acc;
    else if (pc == 1) v = make_float2( acc.y, -acc.x);
    else if (pc == 2) v = make_float2(-acc.x, -acc.y);
    else              v = make_float2(-acc.y,  acc.x);
    Vout[s * 16 + t] = v;
}

// ---------------------------------------------------------------------------
// conv1 (1->1, 8x8, stride 2) + tanh.  x:(256,1,186,186) -> y:(256,1,90,90)
// ---------------------------------------------------------------------------
__global__ __launch_bounds__(256) void k_conv1_tanh(const float* __restrict__ x,
                                                    const float* __restrict__ w,
                                                    const float* __restrict__ bias,
                                                    float* __restrict__ y) {
    int idx = blockIdx.x * 256 + threadIdx.x;      // 256*90*90 exact
    int j = idx % 90;
    int t = idx / 90;
    int i = t % 90;
    int b = t / 90;
    const float* xb = x + b * (186 * 186) + (2 * i) * 186 + 2 * j;
    float acc = bias[0];
    #pragma unroll
    for (int u = 0; u < 8; ++u) {
        #pragma unroll
        for (int v = 0; v < 8; ++v)
            acc = fmaf(w[u * 8 + v], xb[u * 186 + v], acc);
    }
    y[idx] = tanhf(acc);
}

// maxpool 4x4 stride 2 + *pi/2 : (256,90,90) -> (256,44,44)
__global__ __launch_bounds__(256) void k_pool1(const float* __restrict__ y,
                                               float* __restrict__ p) {
    int idx = blockIdx.x * 256 + threadIdx.x;      // 256*44*44 exact
    int j = idx % 44;
    int t = idx / 44;
    int i = t % 44;
    int b = t / 44;
    const float* yb = y + b * 8100 + (2 * i) * 90 + 2 * j;
    float m = -INFINITY;
    #pragma unroll
    for (int u = 0; u < 4; ++u)
        #pragma unroll
        for (int v = 0; v < 4; ++v)
            m = fmaxf(m, yb[u * 90 + v]);
    p[idx] = m * 1.57079632679489662f;
}

// ---------------------------------------------------------------------------
// quanv + relu: (256,44,44) -> (256,4,22,22)
// ---------------------------------------------------------------------------
__global__ __launch_bounds__(256) void k_quanv(const float* __restrict__ p,
                                               const float2* __restrict__ Vg,
                                               float* __restrict__ o) {
    __shared__ float2 V[256];
    V[threadIdx.x] = Vg[threadIdx.x];
    __syncthreads();

    int idx = blockIdx.x * 256 + threadIdx.x;      // 256*22*22 exact
    int j = idx % 22;
    int t = idx / 22;
    int i = t % 22;
    int b = t / 22;
    const float* pb = p + b * 1936 + (2 * i) * 44 + 2 * j;
    float a0 = pb[0], a1 = pb[1], a2 = pb[44], a3 = pb[45];

    float cs[4], sn[4];
    sincosf(0.5f * a0, &sn[0], &cs[0]);
    sincosf(0.5f * a1, &sn[1], &cs[1]);
    sincosf(0.5f * a2, &sn[2], &cs[2]);
    sincosf(0.5f * a3, &sn[3], &cs[3]);

    float c[16];
    #pragma unroll
    for (int tt = 0; tt < 16; ++tt) {
        c[tt] = ((tt & 8) ? sn[0] : cs[0]) * ((tt & 4) ? sn[1] : cs[1]) *
                ((tt & 2) ? sn[2] : cs[2]) * ((tt & 1) ? sn[3] : cs[3]);
    }

    float e0 = 0.f, e1 = 0.f, e2 = 0.f, e3 = 0.f;
    #pragma unroll
    for (int s = 0; s < 16; ++s) {
        float re = 0.f, im = 0.f;
        #pragma unroll
        for (int tt = 0; tt < 16; ++tt) {
            float2 v = V[s * 16 + tt];
            re = fmaf(v.x, c[tt], re);
            im = fmaf(v.y, c[tt], im);
        }
        float pr = re * re + im * im;
        e0 += (s & 8) ? -pr : pr;
        e1 += (s & 4) ? -pr : pr;
        e2 += (s & 2) ? -pr : pr;
        e3 += (s & 1) ? -pr : pr;
    }
    float* ob = o + b * (4 * 484) + i * 22 + j;
    ob[0]    = fmaxf(e0, 0.f);
    ob[484]  = fmaxf(e1, 0.f);
    ob[968]  = fmaxf(e2, 0.f);
    ob[1452] = fmaxf(e3, 0.f);
}

// ---------------------------------------------------------------------------
// conv2 (4->32, 4x4, s1) + relu: (256,4,22,22) -> (256,32,19,19)
// ---------------------------------------------------------------------------
__global__ __launch_bounds__(256) void k_conv2(const float* __restrict__ x,
                                               const float* __restrict__ w,
                                               const float* __restrict__ bias,
                                               float* __restrict__ y) {
    int idx = blockIdx.x * 256 + threadIdx.x;      // 256*32*19*19 exact
    int j = idx % 19;
    int t = idx / 19;
    int i = t % 19;
    t /= 19;
    int oc = t % 32;
    int b  = t / 32;
    const float* xb = x + b * (4 * 484);
    const float* wc = w + oc * 64;
    float acc = bias[oc];
    #pragma unroll
    for (int ic = 0; ic < 4; ++ic) {
        const float* xc = xb + ic * 484;
        #pragma unroll
        for (int u = 0; u < 4; ++u)
            #pragma unroll
            for (int v = 0; v < 4; ++v)
                acc = fmaf(wc[ic * 16 + u * 4 + v], xc[(i + u) * 22 + (j + v)], acc);
    }
    y[idx] = fmaxf(acc, 0.f);
}

// maxpool 4x4 s1: (256,32,19,19) -> (256,32,16,16)
__global__ __launch_bounds__(256) void k_pool2(const float* __restrict__ x,
                                               float* __restrict__ y) {
    int idx = blockIdx.x * 256 + threadIdx.x;      // 256*32*16*16 exact
    int j = idx % 16;
    int t = idx / 16;
    int i = t % 16;
    int c = t / 16;                                 // (b*32+oc)
    const float* xb = x + c * 361 + i * 19 + j;
    float m = -INFINITY;
    #pragma unroll
    for (int u = 0; u < 4; ++u)
        #pragma unroll
        for (int v = 0; v < 4; ++v)
            m = fmaxf(m, xb[u * 19 + v]);
    y[idx] = m;
}

// ---------------------------------------------------------------------------
// conv3 (32->64, 4x4, s1) + relu: (256,32,16,16) -> (256,64,13,13)
// ---------------------------------------------------------------------------
__global__ __launch_bounds__(256) void k_conv3(const float* __restrict__ x,
                                               const float* __restrict__ w,
                                               const float* __restrict__ bias,
                                               float* __restrict__ y) {
    int idx = blockIdx.x * 256 + threadIdx.x;      // 256*64*13*13 exact
    int j = idx % 13;
    int t = idx / 13;
    int i = t % 13;
    t /= 13;
    int oc = t % 64;
    int b  = t / 64;
    const float* xb = x + b * (32 * 256);
    const float* wc = w + oc * (32 * 16);
    float acc = bias[oc];
    for (int ic = 0; ic < 32; ++ic) {
        const float* xc = xb + ic * 256 + i * 16 + j;
        const float* wcc = wc + ic * 16;
        #pragma unroll
        for (int u = 0; u < 4; ++u)
            #pragma unroll
            for (int v = 0; v < 4; ++v)
                acc = fmaf(wcc[u * 4 + v], xc[u * 16 + v], acc);
    }
    y[idx] = fmaxf(acc, 0.f);
}

// maxpool 2x2 s1: (256,64,13,13) -> (256,64,12,12)
__global__ __launch_bounds__(256) void k_pool3(const float* __restrict__ x,
                                               float* __restrict__ y) {
    int idx = blockIdx.x * 256 + threadIdx.x;      // 256*64*12*12 exact
    int j = idx % 12;
    int t = idx / 12;
    int i = t % 12;
    int c = t / 12;                                 // (b*64+oc)
    const float* xb = x + c * 169 + i * 13 + j;
    float m = fmaxf(fmaxf(xb[0], xb[1]), fmaxf(xb[13], xb[14]));
    y[idx] = m;
}

// ---------------------------------------------------------------------------
// conv4 (64->128, 4x4, s2) + relu: (256,64,12,12) -> (256,128,5,5)
// ---------------------------------------------------------------------------
__global__ __launch_bounds__(256) void k_conv4(const float* __restrict__ x,
                                               const float* __restrict__ w,
                                               const float* __restrict__ bias,
                                               float* __restrict__ y) {
    int idx = blockIdx.x * 256 + threadIdx.x;      // 256*128*5*5 exact
    int j = idx % 5;
    int t = idx / 5;
    int i = t % 5;
    t /= 5;
    int oc = t % 128;
    int b  = t / 128;
    const float* xb = x + b * (64 * 144);
    const float* wc = w + oc * (64 * 16);
    float acc = bias[oc];
    for (int ic = 0; ic < 64; ++ic) {
        const float* xc = xb + ic * 144 + (2 * i) * 12 + 2 * j;
        const float* wcc = wc + ic * 16;
        #pragma unroll
        for (int u = 0; u < 4; ++u)
            #pragma unroll
            for (int v = 0; v < 4; ++v)
                acc = fmaf(wcc[u * 4 + v], xc[u * 12 + v], acc);
    }
    y[idx] = fmaxf(acc, 0.f);
}

// ---------------------------------------------------------------------------
// fc layers
// ---------------------------------------------------------------------------
__global__ __launch_bounds__(256) void k_fc1(const float* __restrict__ x,
                                             const float* __restrict__ w,
                                             const float* __restrict__ bias,
                                             float* __restrict__ y) {
    int o = blockIdx.x;                             // 128
    int b = threadIdx.x;                            // 256
    const float4* xb = (const float4*)(x + b * 3200);
    const float4* wo = (const float4*)(w + o * 3200);
    float acc = 0.f;
    for (int k = 0; k < 800; ++k) {
        float4 xv = xb[k], wv = wo[k];
        acc = fmaf(xv.x, wv.x, acc);
        acc = fmaf(xv.y, wv.y, acc);
        acc = fmaf(xv.z, wv.z, acc);
        acc = fmaf(xv.w, wv.w, acc);
    }
    y[b * 128 + o] = fmaxf(acc + bias[o], 0.f);
}

__global__ __launch_bounds__(256) void k_fc2(const float* __restrict__ x,
                                             const float* __restrict__ w,
                                             const float* __restrict__ bias,
                                             float* __restrict__ y) {
    int o = blockIdx.x;                             // 64
    int b = threadIdx.x;                            // 256
    const float4* xb = (const float4*)(x + b * 128);
    const float4* wo = (const float4*)(w + o * 128);
    float acc = 0.f;
    #pragma unroll
    for (int k = 0; k < 32; ++k) {
        float4 xv = xb[k], wv = wo[k];
        acc = fmaf(xv.x, wv.x, acc);
        acc = fmaf(xv.y, wv.y, acc);
        acc = fmaf(xv.z, wv.z, acc);
        acc = fmaf(xv.w, wv.w, acc);
    }
    y[b * 64 + o] = fmaxf(acc + bias[o], 0.f);
}

__global__ __launch_bounds__(256) void k_fc3(const float* __restrict__ x,
                                             const float* __restrict__ w,
                                             const float* __restrict__ bias,
                                             float* __restrict__ y) {
    int o = blockIdx.x;                             // 16
    int b = threadIdx.x;                            // 256
    const float4* xb = (const float4*)(x + b * 64);
    const float4* wo = (const float4*)(w + o * 64);
    float acc = 0.f;
    #pragma unroll
    for (int k = 0; k < 16; ++k) {
        float4 xv = xb[k], wv = wo[k];
        acc = fmaf(xv.x, wv.x, acc);
        acc = fmaf(xv.y, wv.y, acc);
        acc = fmaf(xv.z, wv.z, acc);
        acc = fmaf(xv.w, wv.w, acc);
    }
    y[b * 16 + o] = fmaxf(acc + bias[o], 0.f);
}

__global__ __launch_bounds__(256) void k_fc4_lsm(const float* __restrict__ x,
                                                 const float* __restrict__ w,
                                                 const float* __restrict__ bias,
                                                 float* __restrict__ out) {
    int b = threadIdx.x;                            // 256, single block
    const float* xb = x + b * 16;
    float z0 = bias[0], z1 = bias[1];
    #pragma unroll
    for (int k = 0; k < 16; ++k) {
        z0 = fmaf(w[k],      xb[k], z0);
        z1 = fmaf(w[16 + k], xb[k], z1);
    }
    float m = fmaxf(z0, z1);
    float lse = m + logf(expf(z0 - m) + expf(z1 - m));
    out[b * 2 + 0] = z0 - lse;
    out[b * 2 + 1] = z1 - lse;
}

// ---------------------------------------------------------------------------
extern "C" void kernel_launch(void* const* d_in, const int* in_sizes, int n_in,
                              void* d_out, int out_size, void* d_ws, size_t ws_size,
                              hipStream_t stream) {
    const float* x       = (const float*)d_in[0];
    const float* conv1_w = (const float*)d_in[1];
    const float* conv1_b = (const float*)d_in[2];
    const float* q_w     = (const float*)d_in[3];
    const float* conv2_w = (const float*)d_in[4];
    const float* conv2_b = (const float*)d_in[5];
    const float* conv3_w = (const float*)d_in[6];
    const float* conv3_b = (const float*)d_in[7];
    const float* conv4_w = (const float*)d_in[8];
    const float* conv4_b = (const float*)d_in[9];
    const float* fc1_w   = (const float*)d_in[10];
    const float* fc1_b   = (const float*)d_in[11];
    const float* fc2_w   = (const float*)d_in[12];
    const float* fc2_b   = (const float*)d_in[13];
    const float* fc3_w   = (const float*)d_in[14];
    const float* fc3_b   = (const float*)d_in[15];
    const float* fc4_w   = (const float*)d_in[16];
    const float* fc4_b   = (const float*)d_in[17];
    float* out = (float*)d_out;

    char* ws = (char*)d_ws;
    float2* V = (float2*)ws;                               // 2 KB
    float* A  = (float*)(ws + 4096);                       // up to 9.44 MB
    float* B  = (float*)(ws + 4096 + 9437184);             // up to 11.83 MB

    k_build_V<<<1, 256, 0, stream>>>(q_w, V);
    k_conv1_tanh<<<8100, 256, 0, stream>>>(x, conv1_w, conv1_b, A);
    k_pool1<<<1936, 256, 0, stream>>>(A, B);
    k_quanv<<<484, 256, 0, stream>>>(B, V, A);
    k_conv2<<<11552, 256, 0, stream>>>(A, conv2_w, conv2_b, B);
    k_pool2<<<8192, 256, 0, stream>>>(B, A);
    k_conv3<<<10816, 256, 0, stream>>>(A, conv3_w, conv3_b, B);
    k_pool3<<<9216, 256, 0, stream>>>(B, A);
    k_conv4<<<3200, 256, 0, stream>>>(A, conv4_w, conv4_b, B);
    k_fc1<<<128, 256, 0, stream>>>(B, fc1_w, fc1_b, A);
    k_fc2<<<64, 256, 0, stream>>>(A, fc2_w, fc2_b, B);
    k_fc3<<<16, 256, 0, stream>>>(B, fc3_w, fc3_b, A);
    k_fc4_lsm<<<1, 256, 0, stream>>>(A, fc4_w, fc4_b, out);
}

// Round 2
// 268.068 us; speedup vs baseline: 2.6266x; 2.6266x over previous
//
#include <hip/hip_runtime.h>
#include <hip/hip_bf16.h>
#include <math.h>

// ---------------------------------------------------------------------------
// Hybrid_QuanvModel — round 2: LDS-tiled convs + restructured FCs.
// ---------------------------------------------------------------------------

__device__ __forceinline__ float2 cmul(float2 a, float2 b) {
    return make_float2(a.x * b.x - a.y * b.y, a.x * b.y + a.y * b.x);
}
__device__ __forceinline__ float2 cfma(float2 a, float2 b, float2 acc) {
    acc.x += a.x * b.x - a.y * b.y;
    acc.y += a.x * b.y + a.y * b.x;
    return acc;
}

// ---------------------------------------------------------------------------
// Build V[s][t] = U3[s][t] * (-i)^popcount(t)   (16x16 complex)
// ---------------------------------------------------------------------------
__global__ __launch_bounds__(256) void k_build_V(const float* __restrict__ qw,
                                                 float2* __restrict__ Vout) {
    __shared__ float2 rot[3][4][2][2];
    __shared__ float2 L[16][16];
    __shared__ float2 U[16][16];
    __shared__ float2 T[16][16];

    int tid = threadIdx.x;
    if (tid < 12) {
        int l = tid >> 2, q = tid & 3;
        float phi = qw[(l * 4 + q) * 3 + 0];
        float th  = qw[(l * 4 + q) * 3 + 1];
        float om  = qw[(l * 4 + q) * 3 + 2];
        float c, s;
        sincosf(0.5f * th, &s, &c);
        float sa, ca, sb, cb;
        sincosf(0.5f * (phi + om), &sa, &ca);
        sincosf(0.5f * (phi - om), &sb, &cb);
        rot[l][q][0][0] = make_float2( ca * c, -sa * c);
        rot[l][q][0][1] = make_float2(-cb * s, -sb * s);
        rot[l][q][1][0] = make_float2( cb * s, -sb * s);
        rot[l][q][1][1] = make_float2( ca * c,  sa * c);
    }
    int s = tid >> 4, t = tid & 15;
    U[s][t] = make_float2((s == t) ? 1.f : 0.f, 0.f);
    __syncthreads();

    for (int l = 0; l < 3; ++l) {
        int r = l + 1;
        int ss = s;
        for (int i = 3; i >= 0; --i) {
            int c_ = i, t_ = (i + r) & 3;
            if ((ss >> (3 - c_)) & 1) ss ^= 1 << (3 - t_);
        }
        float2 v = make_float2(1.f, 0.f);
        #pragma unroll
        for (int q = 0; q < 4; ++q) {
            int bs = (ss >> (3 - q)) & 1;
            int bt = (t  >> (3 - q)) & 1;
            v = cmul(v, rot[l][q][bs][bt]);
        }
        L[s][t] = v;
        __syncthreads();
        float2 acc = make_float2(0.f, 0.f);
        #pragma unroll
        for (int k = 0; k < 16; ++k) acc = cfma(L[s][k], U[k][t], acc);
        T[s][t] = acc;
        __syncthreads();
        U[s][t] = T[s][t];
        __syncthreads();
    }
    float2 acc = make_float2(0.f, 0.f);
    #pragma unroll
    for (int k = 0; k < 16; ++k) acc = cfma(U[s][k], U[k][t], acc);
    T[s][t] = acc;
    __syncthreads();
    acc = make_float2(0.f, 0.f);
    #pragma unroll
    for (int k = 0; k < 16; ++k) acc = cfma(T[s][k], U[k][t], acc);
    int pc = __popc(t) & 3;
    float2 v;
    if      (pc == 0) v = acc;
    else if (pc == 1) v = make_float2( acc.y, -acc.x);
    else if (pc == 2) v = make_float2(-acc.x, -acc.y);
    else              v = make_float2(-acc.y,  acc.x);
    Vout[s * 16 + t] = v;
}

// ---------------------------------------------------------------------------
// conv1 (1->1, 8x8, s2) + tanh, LDS strip-tiled.
// x:(256,186,186) -> y:(256,90,90).  grid = 256 img * 3 strips, block 256.
// ---------------------------------------------------------------------------
__global__ __launch_bounds__(256) void k_conv1t(const float* __restrict__ x,
                                                const float* __restrict__ w,
                                                const float* __restrict__ bias,
                                                float* __restrict__ y) {
    __shared__ float Xs[66 * 188];   // 66 input rows, cols padded 186->188
    __shared__ float Wc[64];
    int bid = blockIdx.x;
    int b = bid / 3, strip = bid % 3;
    int i0 = strip * 30;             // 30 output rows per strip
    int tid = threadIdx.x;

    if (tid < 64) Wc[tid] = w[tid];
    const float* xb = x + b * 34596 + (2 * i0) * 186;
    for (int q = tid; q < 66 * 93; q += 256) {
        int r = q / 93, c2 = q % 93;
        float2 v = *(const float2*)(xb + r * 186 + 2 * c2);
        *(float2*)(&Xs[r * 188 + 2 * c2]) = v;
    }
    __syncthreads();

    float bv = bias[0];
    for (int u = tid; u < 270; u += 256) {     // 30 rows * 9 j-groups of 10
        int row = u / 9, jg = u % 9;
        float acc[10];
        #pragma unroll
        for (int j = 0; j < 10; ++j) acc[j] = bv;
        #pragma unroll
        for (int ku = 0; ku < 8; ++ku) {
            const float* rp = &Xs[(2 * row + ku) * 188 + 20 * jg];
            float xr[26];
            #pragma unroll
            for (int k = 0; k < 13; ++k) {
                float2 v = *(const float2*)(rp + 2 * k);
                xr[2 * k] = v.x; xr[2 * k + 1] = v.y;
            }
            float wr[8];
            *(float4*)&wr[0] = *(const float4*)&Wc[ku * 8];
            *(float4*)&wr[4] = *(const float4*)&Wc[ku * 8 + 4];
            #pragma unroll
            for (int j = 0; j < 10; ++j)
                #pragma unroll
                for (int v = 0; v < 8; ++v)
                    acc[j] = fmaf(wr[v], xr[2 * j + v], acc[j]);
        }
        float* yp = y + b * 8100 + (i0 + row) * 90 + jg * 10;
        #pragma unroll
        for (int j = 0; j < 10; ++j) yp[j] = tanhf(acc[j]);
    }
}

// maxpool 4x4 s2 + *pi/2 : (256,90,90) -> (256,44,44)
__global__ __launch_bounds__(256) void k_pool1(const float* __restrict__ y,
                                               float* __restrict__ p) {
    int idx = blockIdx.x * 256 + threadIdx.x;
    int j = idx % 44;
    int t = idx / 44;
    int i = t % 44;
    int b = t / 44;
    const float* yb = y + b * 8100 + (2 * i) * 90 + 2 * j;
    float m = -INFINITY;
    #pragma unroll
    for (int u = 0; u < 4; ++u)
        #pragma unroll
        for (int v = 0; v < 4; ++v)
            m = fmaxf(m, yb[u * 90 + v]);
    p[idx] = m * 1.57079632679489662f;
}

// ---------------------------------------------------------------------------
// quanv + relu: (256,44,44) -> (256,4,22,22)
// ---------------------------------------------------------------------------
__global__ __launch_bounds__(256) void k_quanv(const float* __restrict__ p,
                                               const float2* __restrict__ Vg,
                                               float* __restrict__ o) {
    __shared__ float2 V[256];
    V[threadIdx.x] = Vg[threadIdx.x];
    __syncthreads();

    int idx = blockIdx.x * 256 + threadIdx.x;
    int j = idx % 22;
    int t = idx / 22;
    int i = t % 22;
    int b = t / 22;
    const float* pb = p + b * 1936 + (2 * i) * 44 + 2 * j;
    float a0 = pb[0], a1 = pb[1], a2 = pb[44], a3 = pb[45];

    float cs[4], sn[4];
    sincosf(0.5f * a0, &sn[0], &cs[0]);
    sincosf(0.5f * a1, &sn[1], &cs[1]);
    sincosf(0.5f * a2, &sn[2], &cs[2]);
    sincosf(0.5f * a3, &sn[3], &cs[3]);

    float c[16];
    #pragma unroll
    for (int tt = 0; tt < 16; ++tt) {
        c[tt] = ((tt & 8) ? sn[0] : cs[0]) * ((tt & 4) ? sn[1] : cs[1]) *
                ((tt & 2) ? sn[2] : cs[2]) * ((tt & 1) ? sn[3] : cs[3]);
    }

    float e0 = 0.f, e1 = 0.f, e2 = 0.f, e3 = 0.f;
    #pragma unroll
    for (int s = 0; s < 16; ++s) {
        float re = 0.f, im = 0.f;
        #pragma unroll
        for (int tt = 0; tt < 16; ++tt) {
            float2 v = V[s * 16 + tt];
            re = fmaf(v.x, c[tt], re);
            im = fmaf(v.y, c[tt], im);
        }
        float pr = re * re + im * im;
        e0 += (s & 8) ? -pr : pr;
        e1 += (s & 4) ? -pr : pr;
        e2 += (s & 2) ? -pr : pr;
        e3 += (s & 1) ? -pr : pr;
    }
    float* ob = o + b * (4 * 484) + i * 22 + j;
    ob[0]    = fmaxf(e0, 0.f);
    ob[484]  = fmaxf(e1, 0.f);
    ob[968]  = fmaxf(e2, 0.f);
    ob[1452] = fmaxf(e3, 0.f);
}

// ---------------------------------------------------------------------------
// conv2 (4->32, 4x4, s1) + relu, LDS tiled. (256,4,22,22) -> (256,32,19,19)
// grid = 256 (one image/block), block 640.
// ---------------------------------------------------------------------------
__global__ __launch_bounds__(640) void k_conv2t(const float* __restrict__ x,
                                                const float* __restrict__ w,
                                                const float* __restrict__ bias,
                                                float* __restrict__ y) {
    __shared__ float Xs[4 * 22 * 28];    // rows padded 22->28
    __shared__ float Ws[32 * 68];        // per-oc padded 64->68
    int b = blockIdx.x;
    int tid = threadIdx.x;

    const float* xb = x + b * 1936;
    for (int k = tid; k < 1936; k += 640) {
        int ic = k / 484, rem = k % 484;
        int r = rem / 22, c = rem % 22;
        Xs[ic * 616 + r * 28 + c] = xb[k];
    }
    for (int k = tid; k < 2048; k += 640) {
        Ws[(k >> 6) * 68 + (k & 63)] = w[k];
    }
    __syncthreads();

    if (tid < 608) {
        int oc = tid / 19, i = tid % 19;
        float acc[19];
        float bv = bias[oc];
        #pragma unroll
        for (int j = 0; j < 19; ++j) acc[j] = bv;
        const float* wr = &Ws[oc * 68];
        #pragma unroll
        for (int ic = 0; ic < 4; ++ic) {
            #pragma unroll
            for (int u = 0; u < 4; ++u) {
                const float* rp = &Xs[ic * 616 + (i + u) * 28];
                float xr[22];
                #pragma unroll
                for (int k = 0; k < 5; ++k)
                    *(float4*)&xr[4 * k] = *(const float4*)(rp + 4 * k);
                *(float2*)&xr[20] = *(const float2*)(rp + 20);
                float4 wv = *(const float4*)(wr + ic * 16 + u * 4);
                #pragma unroll
                for (int j = 0; j < 19; ++j) {
                    acc[j] = fmaf(wv.x, xr[j],     acc[j]);
                    acc[j] = fmaf(wv.y, xr[j + 1], acc[j]);
                    acc[j] = fmaf(wv.z, xr[j + 2], acc[j]);
                    acc[j] = fmaf(wv.w, xr[j + 3], acc[j]);
                }
            }
        }
        float* yp = y + b * 11552 + oc * 361 + i * 19;
        #pragma unroll
        for (int j = 0; j < 19; ++j) yp[j] = fmaxf(acc[j], 0.f);
    }
}

// maxpool 4x4 s1: (256,32,19,19) -> (256,32,16,16)
__global__ __launch_bounds__(256) void k_pool2(const float* __restrict__ x,
                                               float* __restrict__ y) {
    int idx = blockIdx.x * 256 + threadIdx.x;
    int j = idx % 16;
    int t = idx / 16;
    int i = t % 16;
    int c = t / 16;
    const float* xb = x + c * 361 + i * 19 + j;
    float m = -INFINITY;
    #pragma unroll
    for (int u = 0; u < 4; ++u)
        #pragma unroll
        for (int v = 0; v < 4; ++v)
            m = fmaxf(m, xb[u * 19 + v]);
    y[idx] = m;
}

// ---------------------------------------------------------------------------
// conv3 (32->64, 4x4, s1) + relu, LDS tiled. (256,32,16,16) -> (256,64,13,13)
// grid = 256 img * 4 ocgroups(16), block 256.
// ---------------------------------------------------------------------------
__global__ __launch_bounds__(256) void k_conv3t(const float* __restrict__ x,
                                                const float* __restrict__ w,
                                                const float* __restrict__ bias,
                                                float* __restrict__ y) {
    __shared__ float Xs[32 * 16 * 20];   // rows padded 16->20 (40 KB)
    __shared__ float Ws[16 * 516];       // per-oc padded 512->516 (33 KB)
    int bid = blockIdx.x;
    int b = bid >> 2, ocg = bid & 3;
    int tid = threadIdx.x;

    const float* xb = x + b * 8192;
    for (int k = tid; k < 8192; k += 256) {
        int ic = k >> 8, r = (k >> 4) & 15, c = k & 15;
        Xs[ic * 320 + r * 20 + c] = xb[k];
    }
    const float* wb = w + ocg * 8192;
    for (int k = tid; k < 8192; k += 256) {
        Ws[(k >> 9) * 516 + (k & 511)] = wb[k];
    }
    __syncthreads();

    if (tid < 208) {
        int oc = tid / 13, i = tid % 13;
        float acc[13];
        float bv = bias[ocg * 16 + oc];
        #pragma unroll
        for (int j = 0; j < 13; ++j) acc[j] = bv;
        const float* wr = &Ws[oc * 516];
        for (int ic = 0; ic < 32; ++ic) {
            const float* xc = &Xs[ic * 320];
            #pragma unroll
            for (int u = 0; u < 4; ++u) {
                const float* rp = xc + (i + u) * 20;
                float xr[16];
                #pragma unroll
                for (int k = 0; k < 4; ++k)
                    *(float4*)&xr[4 * k] = *(const float4*)(rp + 4 * k);
                float4 wv = *(const float4*)(wr + ic * 16 + u * 4);
                #pragma unroll
                for (int j = 0; j < 13; ++j) {
                    acc[j] = fmaf(wv.x, xr[j],     acc[j]);
                    acc[j] = fmaf(wv.y, xr[j + 1], acc[j]);
                    acc[j] = fmaf(wv.z, xr[j + 2], acc[j]);
                    acc[j] = fmaf(wv.w, xr[j + 3], acc[j]);
                }
            }
        }
        float* yp = y + b * 10816 + (ocg * 16 + oc) * 169 + i * 13;
        #pragma unroll
        for (int j = 0; j < 13; ++j) yp[j] = fmaxf(acc[j], 0.f);
    }
}

// maxpool 2x2 s1: (256,64,13,13) -> (256,64,12,12)
__global__ __launch_bounds__(256) void k_pool3(const float* __restrict__ x,
                                               float* __restrict__ y) {
    int idx = blockIdx.x * 256 + threadIdx.x;
    int j = idx % 12;
    int t = idx / 12;
    int i = t % 12;
    int c = t / 12;
    const float* xb = x + c * 169 + i * 13 + j;
    float m = fmaxf(fmaxf(xb[0], xb[1]), fmaxf(xb[13], xb[14]));
    y[idx] = m;
}

// ---------------------------------------------------------------------------
// conv4 (64->128, 4x4, s2) + relu, LDS tiled. (256,64,12,12) -> (256,128,5,5)
// grid = 256 img * 2 ocgroups(64), block 320 (64 oc * 5 rows).
// ---------------------------------------------------------------------------
__global__ __launch_bounds__(320) void k_conv4t(const float* __restrict__ x,
                                                const float* __restrict__ w,
                                                const float* __restrict__ bias,
                                                float* __restrict__ y) {
    __shared__ float Xs[64 * 144];       // 36 KB
    __shared__ float Ws[64 * 132];       // 8-ic chunk, padded 128->132 (33.8 KB)
    int bid = blockIdx.x;
    int b = bid >> 1, ocg = bid & 1;
    int ocB = ocg * 64;
    int tid = threadIdx.x;

    const float* xb = x + b * 9216;
    for (int k = tid; k < 9216; k += 320) Xs[k] = xb[k];

    int oc = tid / 5, i = tid % 5;
    float acc[5];
    float bv = bias[ocB + oc];
    #pragma unroll
    for (int j = 0; j < 5; ++j) acc[j] = bv;

    for (int cc = 0; cc < 8; ++cc) {
        __syncthreads();
        for (int k = tid; k < 8192; k += 320) {
            int o = k >> 7, r = k & 127;
            Ws[o * 132 + r] = w[(ocB + o) * 1024 + cc * 128 + r];
        }
        __syncthreads();
        #pragma unroll
        for (int icl = 0; icl < 8; ++icl) {
            const float* xc = &Xs[(cc * 8 + icl) * 144];
            #pragma unroll
            for (int u = 0; u < 4; ++u) {
                const float* rp = xc + (2 * i + u) * 12;
                float xr[12];
                #pragma unroll
                for (int k = 0; k < 3; ++k)
                    *(float4*)&xr[4 * k] = *(const float4*)(rp + 4 * k);
                float4 wv = *(const float4*)&Ws[oc * 132 + icl * 16 + u * 4];
                #pragma unroll
                for (int j = 0; j < 5; ++j) {
                    acc[j] = fmaf(wv.x, xr[2 * j],     acc[j]);
                    acc[j] = fmaf(wv.y, xr[2 * j + 1], acc[j]);
                    acc[j] = fmaf(wv.z, xr[2 * j + 2], acc[j]);
                    acc[j] = fmaf(wv.w, xr[2 * j + 3], acc[j]);
                }
            }
        }
    }
    float* yp = y + b * 3200 + (ocB + oc) * 25 + i * 5;
    #pragma unroll
    for (int j = 0; j < 5; ++j) yp[j] = fmaxf(acc[j], 0.f);
}

// ---------------------------------------------------------------------------
// fc1: (256,3200) @ (128,3200)^T + relu.  K spanned by lanes (coalesced).
// grid = 64 imgGroups(4) * 4 ocGroups(32) = 256 blocks, block 256 (4 waves).
// ---------------------------------------------------------------------------
__global__ __launch_bounds__(256) void k_fc1t(const float* __restrict__ x,
                                              const float* __restrict__ w,
                                              const float* __restrict__ bias,
                                              float* __restrict__ y) {
    __shared__ float Ls[4][32][65];
    int bid = blockIdx.x;
    int ig = bid >> 2, ocg = bid & 3;
    int imgB = ig * 4, ocB = ocg * 32;
    int tid = threadIdx.x, lane = tid & 63, wv = tid >> 6;
    int ocW = ocB + wv * 8;

    float acc[8][4];
    #pragma unroll
    for (int o = 0; o < 8; ++o)
        #pragma unroll
        for (int m = 0; m < 4; ++m) acc[o][m] = 0.f;

    for (int it = 0; it < 25; ++it) {
        int k = it * 128 + lane * 2;
        float2 xv[4];
        #pragma unroll
        for (int m = 0; m < 4; ++m)
            xv[m] = *(const float2*)&x[(imgB + m) * 3200 + k];
        #pragma unroll
        for (int o = 0; o < 8; ++o) {
            float2 wvv = *(const float2*)&w[(ocW + o) * 3200 + k];
            #pragma unroll
            for (int m = 0; m < 4; ++m) {
                acc[o][m] = fmaf(wvv.x, xv[m].x, acc[o][m]);
                acc[o][m] = fmaf(wvv.y, xv[m].y, acc[o][m]);
            }
        }
    }
    #pragma unroll
    for (int o = 0; o < 8; ++o)
        #pragma unroll
        for (int m = 0; m < 4; ++m)
            Ls[wv][o * 4 + m][lane] = acc[o][m];
    __syncthreads();

    if (tid < 128) {
        int w2 = tid >> 5, r = tid & 31;
        const float* p = Ls[w2][r];
        float s = 0.f;
        #pragma unroll
        for (int c = 0; c < 64; ++c) s += p[c];
        int o = r >> 2, m = r & 3;
        int oc = ocB + w2 * 8 + o;
        y[(imgB + m) * 128 + oc] = fmaxf(s + bias[oc], 0.f);
    }
}

// ---------------------------------------------------------------------------
// fused fc2+relu, fc3+relu, fc4+log_softmax.  grid 256 (img), block 64.
// ---------------------------------------------------------------------------
__global__ __launch_bounds__(64) void k_fc_tail(const float* __restrict__ x,
                                                const float* __restrict__ w2,
                                                const float* __restrict__ b2,
                                                const float* __restrict__ w3,
                                                const float* __restrict__ b3,
                                                const float* __restrict__ w4,
                                                const float* __restrict__ b4,
                                                float* __restrict__ out) {
    __shared__ float xs[128], h2[64], h3[16];
    int img = blockIdx.x;
    int lane = threadIdx.x;

    *(float2*)&xs[lane * 2] = *(const float2*)&x[img * 128 + lane * 2];
    __syncthreads();

    float a = b2[lane];
    const float4* wp = (const float4*)&w2[lane * 128];
    const float4* xp = (const float4*)xs;
    #pragma unroll
    for (int k = 0; k < 32; ++k) {
        float4 wv = wp[k], xv = xp[k];
        a = fmaf(wv.x, xv.x, a);
        a = fmaf(wv.y, xv.y, a);
        a = fmaf(wv.z, xv.z, a);
        a = fmaf(wv.w, xv.w, a);
    }
    h2[lane] = fmaxf(a, 0.f);
    __syncthreads();

    if (lane < 16) {
        float a3 = b3[lane];
        const float4* w3p = (const float4*)&w3[lane * 64];
        const float4* h2p = (const float4*)h2;
        #pragma unroll
        for (int k = 0; k < 16; ++k) {
            float4 wv = w3p[k], xv = h2p[k];
            a3 = fmaf(wv.x, xv.x, a3);
            a3 = fmaf(wv.y, xv.y, a3);
            a3 = fmaf(wv.z, xv.z, a3);
            a3 = fmaf(wv.w, xv.w, a3);
        }
        h3[lane] = fmaxf(a3, 0.f);
    }
    __syncthreads();

    if (lane == 0) {
        float z0 = b4[0], z1 = b4[1];
        #pragma unroll
        for (int k = 0; k < 16; ++k) {
            z0 = fmaf(w4[k],      h3[k], z0);
            z1 = fmaf(w4[16 + k], h3[k], z1);
        }
        float m = fmaxf(z0, z1);
        float lse = m + logf(expf(z0 - m) + expf(z1 - m));
        out[img * 2 + 0] = z0 - lse;
        out[img * 2 + 1] = z1 - lse;
    }
}

// ---------------------------------------------------------------------------
extern "C" void kernel_launch(void* const* d_in, const int* in_sizes, int n_in,
                              void* d_out, int out_size, void* d_ws, size_t ws_size,
                              hipStream_t stream) {
    const float* x       = (const float*)d_in[0];
    const float* conv1_w = (const float*)d_in[1];
    const float* conv1_b = (const float*)d_in[2];
    const float* q_w     = (const float*)d_in[3];
    const float* conv2_w = (const float*)d_in[4];
    const float* conv2_b = (const float*)d_in[5];
    const float* conv3_w = (const float*)d_in[6];
    const float* conv3_b = (const float*)d_in[7];
    const float* conv4_w = (const float*)d_in[8];
    const float* conv4_b = (const float*)d_in[9];
    const float* fc1_w   = (const float*)d_in[10];
    const float* fc1_b   = (const float*)d_in[11];
    const float* fc2_w   = (const float*)d_in[12];
    const float* fc2_b   = (const float*)d_in[13];
    const float* fc3_w   = (const float*)d_in[14];
    const float* fc3_b   = (const float*)d_in[15];
    const float* fc4_w   = (const float*)d_in[16];
    const float* fc4_b   = (const float*)d_in[17];
    float* out = (float*)d_out;

    char* ws = (char*)d_ws;
    float2* V = (float2*)ws;                               // 2 KB
    float* A  = (float*)(ws + 4096);                       // up to 9.44 MB
    float* B  = (float*)(ws + 4096 + 9437184);             // up to 11.83 MB

    k_build_V<<<1, 256, 0, stream>>>(q_w, V);
    k_conv1t<<<768, 256, 0, stream>>>(x, conv1_w, conv1_b, A);
    k_pool1<<<1936, 256, 0, stream>>>(A, B);
    k_quanv<<<484, 256, 0, stream>>>(B, V, A);
    k_conv2t<<<256, 640, 0, stream>>>(A, conv2_w, conv2_b, B);
    k_pool2<<<8192, 256, 0, stream>>>(B, A);
    k_conv3t<<<1024, 256, 0, stream>>>(A, conv3_w, conv3_b, B);
    k_pool3<<<9216, 256, 0, stream>>>(B, A);
    k_conv4t<<<512, 320, 0, stream>>>(A, conv4_w, conv4_b, B);
    k_fc1t<<<256, 256, 0, stream>>>(B, fc1_w, fc1_b, A);
    k_fc_tail<<<256, 64, 0, stream>>>(A, fc2_w, fc2_b, fc3_w, fc3_b,
                                      fc4_w, fc4_b, out);
}

// Round 3
// 208.150 us; speedup vs baseline: 3.3827x; 1.2879x over previous
//
#include <hip/hip_runtime.h>
#include <hip/hip_bf16.h>
#include <math.h>

// ---------------------------------------------------------------------------
// Hybrid_QuanvModel — round 3: conv3 (2oc x 13col threads, W via L2) and
// conv4 (K-split-4, 4oc x 5col threads, W via L2) redesigned.
// ---------------------------------------------------------------------------

__device__ __forceinline__ float2 cmul(float2 a, float2 b) {
    return make_float2(a.x * b.x - a.y * b.y, a.x * b.y + a.y * b.x);
}
__device__ __forceinline__ float2 cfma(float2 a, float2 b, float2 acc) {
    acc.x += a.x * b.x - a.y * b.y;
    acc.y += a.x * b.y + a.y * b.x;
    return acc;
}

// ---------------------------------------------------------------------------
// Build V[s][t] = U3[s][t] * (-i)^popcount(t)   (16x16 complex)
// ---------------------------------------------------------------------------
__global__ __launch_bounds__(256) void k_build_V(const float* __restrict__ qw,
                                                 float2* __restrict__ Vout) {
    __shared__ float2 rot[3][4][2][2];
    __shared__ float2 L[16][16];
    __shared__ float2 U[16][16];
    __shared__ float2 T[16][16];

    int tid = threadIdx.x;
    if (tid < 12) {
        int l = tid >> 2, q = tid & 3;
        float phi = qw[(l * 4 + q) * 3 + 0];
        float th  = qw[(l * 4 + q) * 3 + 1];
        float om  = qw[(l * 4 + q) * 3 + 2];
        float c, s;
        sincosf(0.5f * th, &s, &c);
        float sa, ca, sb, cb;
        sincosf(0.5f * (phi + om), &sa, &ca);
        sincosf(0.5f * (phi - om), &sb, &cb);
        rot[l][q][0][0] = make_float2( ca * c, -sa * c);
        rot[l][q][0][1] = make_float2(-cb * s, -sb * s);
        rot[l][q][1][0] = make_float2( cb * s, -sb * s);
        rot[l][q][1][1] = make_float2( ca * c,  sa * c);
    }
    int s = tid >> 4, t = tid & 15;
    U[s][t] = make_float2((s == t) ? 1.f : 0.f, 0.f);
    __syncthreads();

    for (int l = 0; l < 3; ++l) {
        int r = l + 1;
        int ss = s;
        for (int i = 3; i >= 0; --i) {
            int c_ = i, t_ = (i + r) & 3;
            if ((ss >> (3 - c_)) & 1) ss ^= 1 << (3 - t_);
        }
        float2 v = make_float2(1.f, 0.f);
        #pragma unroll
        for (int q = 0; q < 4; ++q) {
            int bs = (ss >> (3 - q)) & 1;
            int bt = (t  >> (3 - q)) & 1;
            v = cmul(v, rot[l][q][bs][bt]);
        }
        L[s][t] = v;
        __syncthreads();
        float2 acc = make_float2(0.f, 0.f);
        #pragma unroll
        for (int k = 0; k < 16; ++k) acc = cfma(L[s][k], U[k][t], acc);
        T[s][t] = acc;
        __syncthreads();
        U[s][t] = T[s][t];
        __syncthreads();
    }
    float2 acc = make_float2(0.f, 0.f);
    #pragma unroll
    for (int k = 0; k < 16; ++k) acc = cfma(U[s][k], U[k][t], acc);
    T[s][t] = acc;
    __syncthreads();
    acc = make_float2(0.f, 0.f);
    #pragma unroll
    for (int k = 0; k < 16; ++k) acc = cfma(T[s][k], U[k][t], acc);
    int pc = __popc(t) & 3;
    float2 v;
    if      (pc == 0) v = acc;
    else if (pc == 1) v = make_float2( acc.y, -acc.x);
    else if (pc == 2) v = make_float2(-acc.x, -acc.y);
    else              v = make_float2(-acc.y,  acc.x);
    Vout[s * 16 + t] = v;
}

// ---------------------------------------------------------------------------
// conv1 (1->1, 8x8, s2) + tanh, LDS strip-tiled.
// ---------------------------------------------------------------------------
__global__ __launch_bounds__(256) void k_conv1t(const float* __restrict__ x,
                                                const float* __restrict__ w,
                                                const float* __restrict__ bias,
                                                float* __restrict__ y) {
    __shared__ float Xs[66 * 188];
    __shared__ float Wc[64];
    int bid = blockIdx.x;
    int b = bid / 3, strip = bid % 3;
    int i0 = strip * 30;
    int tid = threadIdx.x;

    if (tid < 64) Wc[tid] = w[tid];
    const float* xb = x + b * 34596 + (2 * i0) * 186;
    for (int q = tid; q < 66 * 93; q += 256) {
        int r = q / 93, c2 = q % 93;
        float2 v = *(const float2*)(xb + r * 186 + 2 * c2);
        *(float2*)(&Xs[r * 188 + 2 * c2]) = v;
    }
    __syncthreads();

    float bv = bias[0];
    for (int u = tid; u < 270; u += 256) {
        int row = u / 9, jg = u % 9;
        float acc[10];
        #pragma unroll
        for (int j = 0; j < 10; ++j) acc[j] = bv;
        #pragma unroll
        for (int ku = 0; ku < 8; ++ku) {
            const float* rp = &Xs[(2 * row + ku) * 188 + 20 * jg];
            float xr[26];
            #pragma unroll
            for (int k = 0; k < 13; ++k) {
                float2 v = *(const float2*)(rp + 2 * k);
                xr[2 * k] = v.x; xr[2 * k + 1] = v.y;
            }
            float wr[8];
            *(float4*)&wr[0] = *(const float4*)&Wc[ku * 8];
            *(float4*)&wr[4] = *(const float4*)&Wc[ku * 8 + 4];
            #pragma unroll
            for (int j = 0; j < 10; ++j)
                #pragma unroll
                for (int v = 0; v < 8; ++v)
                    acc[j] = fmaf(wr[v], xr[2 * j + v], acc[j]);
        }
        float* yp = y + b * 8100 + (i0 + row) * 90 + jg * 10;
        #pragma unroll
        for (int j = 0; j < 10; ++j) yp[j] = tanhf(acc[j]);
    }
}

// maxpool 4x4 s2 + *pi/2 : (256,90,90) -> (256,44,44)
__global__ __launch_bounds__(256) void k_pool1(const float* __restrict__ y,
                                               float* __restrict__ p) {
    int idx = blockIdx.x * 256 + threadIdx.x;
    int j = idx % 44;
    int t = idx / 44;
    int i = t % 44;
    int b = t / 44;
    const float* yb = y + b * 8100 + (2 * i) * 90 + 2 * j;
    float m = -INFINITY;
    #pragma unroll
    for (int u = 0; u < 4; ++u)
        #pragma unroll
        for (int v = 0; v < 4; ++v)
            m = fmaxf(m, yb[u * 90 + v]);
    p[idx] = m * 1.57079632679489662f;
}

// ---------------------------------------------------------------------------
// quanv + relu: (256,44,44) -> (256,4,22,22)
// ---------------------------------------------------------------------------
__global__ __launch_bounds__(256) void k_quanv(const float* __restrict__ p,
                                               const float2* __restrict__ Vg,
                                               float* __restrict__ o) {
    __shared__ float2 V[256];
    V[threadIdx.x] = Vg[threadIdx.x];
    __syncthreads();

    int idx = blockIdx.x * 256 + threadIdx.x;
    int j = idx % 22;
    int t = idx / 22;
    int i = t % 22;
    int b = t / 22;
    const float* pb = p + b * 1936 + (2 * i) * 44 + 2 * j;
    float a0 = pb[0], a1 = pb[1], a2 = pb[44], a3 = pb[45];

    float cs[4], sn[4];
    sincosf(0.5f * a0, &sn[0], &cs[0]);
    sincosf(0.5f * a1, &sn[1], &cs[1]);
    sincosf(0.5f * a2, &sn[2], &cs[2]);
    sincosf(0.5f * a3, &sn[3], &cs[3]);

    float c[16];
    #pragma unroll
    for (int tt = 0; tt < 16; ++tt) {
        c[tt] = ((tt & 8) ? sn[0] : cs[0]) * ((tt & 4) ? sn[1] : cs[1]) *
                ((tt & 2) ? sn[2] : cs[2]) * ((tt & 1) ? sn[3] : cs[3]);
    }

    float e0 = 0.f, e1 = 0.f, e2 = 0.f, e3 = 0.f;
    #pragma unroll
    for (int s = 0; s < 16; ++s) {
        float re = 0.f, im = 0.f;
        #pragma unroll
        for (int tt = 0; tt < 16; ++tt) {
            float2 v = V[s * 16 + tt];
            re = fmaf(v.x, c[tt], re);
            im = fmaf(v.y, c[tt], im);
        }
        float pr = re * re + im * im;
        e0 += (s & 8) ? -pr : pr;
        e1 += (s & 4) ? -pr : pr;
        e2 += (s & 2) ? -pr : pr;
        e3 += (s & 1) ? -pr : pr;
    }
    float* ob = o + b * (4 * 484) + i * 22 + j;
    ob[0]    = fmaxf(e0, 0.f);
    ob[484]  = fmaxf(e1, 0.f);
    ob[968]  = fmaxf(e2, 0.f);
    ob[1452] = fmaxf(e3, 0.f);
}

// ---------------------------------------------------------------------------
// conv2 (4->32, 4x4, s1) + relu, LDS tiled. (256,4,22,22) -> (256,32,19,19)
// ---------------------------------------------------------------------------
__global__ __launch_bounds__(640) void k_conv2t(const float* __restrict__ x,
                                                const float* __restrict__ w,
                                                const float* __restrict__ bias,
                                                float* __restrict__ y) {
    __shared__ float Xs[4 * 22 * 28];
    __shared__ float Ws[32 * 68];
    int b = blockIdx.x;
    int tid = threadIdx.x;

    const float* xb = x + b * 1936;
    for (int k = tid; k < 1936; k += 640) {
        int ic = k / 484, rem = k % 484;
        int r = rem / 22, c = rem % 22;
        Xs[ic * 616 + r * 28 + c] = xb[k];
    }
    for (int k = tid; k < 2048; k += 640) {
        Ws[(k >> 6) * 68 + (k & 63)] = w[k];
    }
    __syncthreads();

    if (tid < 608) {
        int oc = tid / 19, i = tid % 19;
        float acc[19];
        float bv = bias[oc];
        #pragma unroll
        for (int j = 0; j < 19; ++j) acc[j] = bv;
        const float* wr = &Ws[oc * 68];
        #pragma unroll
        for (int ic = 0; ic < 4; ++ic) {
            #pragma unroll
            for (int u = 0; u < 4; ++u) {
                const float* rp = &Xs[ic * 616 + (i + u) * 28];
                float xr[22];
                #pragma unroll
                for (int k = 0; k < 5; ++k)
                    *(float4*)&xr[4 * k] = *(const float4*)(rp + 4 * k);
                *(float2*)&xr[20] = *(const float2*)(rp + 20);
                float4 wv = *(const float4*)(wr + ic * 16 + u * 4);
                #pragma unroll
                for (int j = 0; j < 19; ++j) {
                    acc[j] = fmaf(wv.x, xr[j],     acc[j]);
                    acc[j] = fmaf(wv.y, xr[j + 1], acc[j]);
                    acc[j] = fmaf(wv.z, xr[j + 2], acc[j]);
                    acc[j] = fmaf(wv.w, xr[j + 3], acc[j]);
                }
            }
        }
        float* yp = y + b * 11552 + oc * 361 + i * 19;
        #pragma unroll
        for (int j = 0; j < 19; ++j) yp[j] = fmaxf(acc[j], 0.f);
    }
}

// maxpool 4x4 s1: (256,32,19,19) -> (256,32,16,16)
__global__ __launch_bounds__(256) void k_pool2(const float* __restrict__ x,
                                               float* __restrict__ y) {
    int idx = blockIdx.x * 256 + threadIdx.x;
    int j = idx % 16;
    int t = idx / 16;
    int i = t % 16;
    int c = t / 16;
    const float* xb = x + c * 361 + i * 19 + j;
    float m = -INFINITY;
    #pragma unroll
    for (int u = 0; u < 4; ++u)
        #pragma unroll
        for (int v = 0; v < 4; ++v)
            m = fmaxf(m, xb[u * 19 + v]);
    y[idx] = m;
}

// ---------------------------------------------------------------------------
// conv3 (32->64, 4x4, s1) + relu.  (256,32,16,16) -> (256,64,13,13)
// grid = 256 (img), block 416 = 32 ocpairs x 13 rows.  X in LDS (stride 20,
// 2-way-max bank aliasing = free), W streamed from L2 on the VMEM pipe.
// ---------------------------------------------------------------------------
__global__ __launch_bounds__(416) void k_conv3n(const float* __restrict__ x,
                                                const float* __restrict__ w,
                                                const float* __restrict__ bias,
                                                float* __restrict__ y) {
    __shared__ float Xs[32 * 320];     // [ic][r*20+c], 41 KB
    int b = blockIdx.x;
    int tid = threadIdx.x;

    const float* xb = x + b * 8192;
    for (int k = tid; k < 2048; k += 416) {
        int ic = k >> 6, rem = k & 63;
        int r = rem >> 2, c4 = rem & 3;
        float4 v = *(const float4*)(xb + ic * 256 + r * 16 + c4 * 4);
        *(float4*)(&Xs[ic * 320 + r * 20 + c4 * 4]) = v;
    }
    __syncthreads();

    int ocp = tid / 13, i = tid % 13;
    int oc0 = ocp * 2;
    float acc0[13], acc1[13];
    float bv0 = bias[oc0], bv1 = bias[oc0 + 1];
    #pragma unroll
    for (int j = 0; j < 13; ++j) { acc0[j] = bv0; acc1[j] = bv1; }

    const float* w0 = w + oc0 * 512;
    for (int ic = 0; ic < 32; ++ic) {
        const float* xc = &Xs[ic * 320 + i * 20];
        #pragma unroll
        for (int u = 0; u < 4; ++u) {
            float xr[16];
            const float* rp = xc + u * 20;
            #pragma unroll
            for (int k = 0; k < 4; ++k)
                *(float4*)&xr[4 * k] = *(const float4*)(rp + 4 * k);
            float4 wa = *(const float4*)(w0 + ic * 16 + u * 4);
            float4 wb = *(const float4*)(w0 + 512 + ic * 16 + u * 4);
            #pragma unroll
            for (int j = 0; j < 13; ++j) {
                acc0[j] = fmaf(wa.x, xr[j],     acc0[j]);
                acc0[j] = fmaf(wa.y, xr[j + 1], acc0[j]);
                acc0[j] = fmaf(wa.z, xr[j + 2], acc0[j]);
                acc0[j] = fmaf(wa.w, xr[j + 3], acc0[j]);
                acc1[j] = fmaf(wb.x, xr[j],     acc1[j]);
                acc1[j] = fmaf(wb.y, xr[j + 1], acc1[j]);
                acc1[j] = fmaf(wb.z, xr[j + 2], acc1[j]);
                acc1[j] = fmaf(wb.w, xr[j + 3], acc1[j]);
            }
        }
    }
    float* yp = y + b * 10816 + oc0 * 169 + i * 13;
    #pragma unroll
    for (int j = 0; j < 13; ++j) {
        yp[j]       = fmaxf(acc0[j], 0.f);
        yp[169 + j] = fmaxf(acc1[j], 0.f);
    }
}

// maxpool 2x2 s1: (256,64,13,13) -> (256,64,12,12)
__global__ __launch_bounds__(256) void k_pool3(const float* __restrict__ x,
                                               float* __restrict__ y) {
    int idx = blockIdx.x * 256 + threadIdx.x;
    int j = idx % 12;
    int t = idx / 12;
    int i = t % 12;
    int c = t / 12;
    const float* xb = x + c * 169 + i * 13 + j;
    float m = fmaxf(fmaxf(xb[0], xb[1]), fmaxf(xb[13], xb[14]));
    y[idx] = m;
}

// ---------------------------------------------------------------------------
// conv4 (64->128, 4x4, s2) partials, K-split-4.
// grid = 256 img * 4 kq, block 160 = 32 ocquads x 5 rows.  Per (ic,u):
// 3 LDS b128 X-reads feed 80 FMAs; weights via L2 (VMEM pipe).
// ---------------------------------------------------------------------------
__global__ __launch_bounds__(160) void k_conv4p(const float* __restrict__ x,
                                                const float* __restrict__ w,
                                                float* __restrict__ part) {
    __shared__ float Xs[2304];         // 16 ic x 144
    int bid = blockIdx.x;
    int b = bid >> 2, kq = bid & 3;
    int ic0 = kq * 16;
    int tid = threadIdx.x;

    const float* xb = x + b * 9216 + ic0 * 144;
    for (int k = tid; k < 576; k += 160)
        *(float4*)&Xs[k * 4] = *(const float4*)(xb + k * 4);
    __syncthreads();

    int ocq = tid / 5, i = tid % 5;
    int oc0 = ocq * 4;
    float acc[4][5];
    #pragma unroll
    for (int o = 0; o < 4; ++o)
        #pragma unroll
        for (int j = 0; j < 5; ++j) acc[o][j] = 0.f;

    const float* wb = w + oc0 * 1024 + ic0 * 16;
    for (int ic = 0; ic < 16; ++ic) {
        const float* xc = &Xs[ic * 144];
        #pragma unroll
        for (int u = 0; u < 4; ++u) {
            const float* rp = xc + (2 * i + u) * 12;
            float xr[12];
            #pragma unroll
            for (int k = 0; k < 3; ++k)
                *(float4*)&xr[4 * k] = *(const float4*)(rp + 4 * k);
            float4 w0 = *(const float4*)(wb +    0 + ic * 16 + u * 4);
            float4 w1 = *(const float4*)(wb + 1024 + ic * 16 + u * 4);
            float4 w2 = *(const float4*)(wb + 2048 + ic * 16 + u * 4);
            float4 w3 = *(const float4*)(wb + 3072 + ic * 16 + u * 4);
            #pragma unroll
            for (int j = 0; j < 5; ++j) {
                float x0 = xr[2 * j], x1 = xr[2 * j + 1];
                float x2 = xr[2 * j + 2], x3 = xr[2 * j + 3];
                acc[0][j] = fmaf(w0.x, x0, acc[0][j]);
                acc[0][j] = fmaf(w0.y, x1, acc[0][j]);
                acc[0][j] = fmaf(w0.z, x2, acc[0][j]);
                acc[0][j] = fmaf(w0.w, x3, acc[0][j]);
                acc[1][j] = fmaf(w1.x, x0, acc[1][j]);
                acc[1][j] = fmaf(w1.y, x1, acc[1][j]);
                acc[1][j] = fmaf(w1.z, x2, acc[1][j]);
                acc[1][j] = fmaf(w1.w, x3, acc[1][j]);
                acc[2][j] = fmaf(w2.x, x0, acc[2][j]);
                acc[2][j] = fmaf(w2.y, x1, acc[2][j]);
                acc[2][j] = fmaf(w2.z, x2, acc[2][j]);
                acc[2][j] = fmaf(w2.w, x3, acc[2][j]);
                acc[3][j] = fmaf(w3.x, x0, acc[3][j]);
                acc[3][j] = fmaf(w3.y, x1, acc[3][j]);
                acc[3][j] = fmaf(w3.z, x2, acc[3][j]);
                acc[3][j] = fmaf(w3.w, x3, acc[3][j]);
            }
        }
    }
    float* pp = part + kq * 819200 + b * 3200 + oc0 * 25 + i * 5;
    #pragma unroll
    for (int o = 0; o < 4; ++o)
        #pragma unroll
        for (int j = 0; j < 5; ++j) pp[o * 25 + j] = acc[o][j];
}

// reduce 4 K-partials + bias + relu -> conv4 out (256,128,5,5)
__global__ __launch_bounds__(256) void k_c4red(const float* __restrict__ part,
                                               const float* __restrict__ bias,
                                               float* __restrict__ y) {
    int idx = blockIdx.x * 256 + threadIdx.x;       // 819200 exact
    float s = part[idx] + part[idx + 819200] + part[idx + 1638400]
            + part[idx + 2457600];
    int oc = (idx / 25) & 127;
    y[idx] = fmaxf(s + bias[oc], 0.f);
}

// ---------------------------------------------------------------------------
// fc1: (256,3200) @ (128,3200)^T + relu.
// ---------------------------------------------------------------------------
__global__ __launch_bounds__(256) void k_fc1t(const float* __restrict__ x,
                                              const float* __restrict__ w,
                                              const float* __restrict__ bias,
                                              float* __restrict__ y) {
    __shared__ float Ls[4][32][65];
    int bid = blockIdx.x;
    int ig = bid >> 2, ocg = bid & 3;
    int imgB = ig * 4, ocB = ocg * 32;
    int tid = threadIdx.x, lane = tid & 63, wv = tid >> 6;
    int ocW = ocB + wv * 8;

    float acc[8][4];
    #pragma unroll
    for (int o = 0; o < 8; ++o)
        #pragma unroll
        for (int m = 0; m < 4; ++m) acc[o][m] = 0.f;

    for (int it = 0; it < 25; ++it) {
        int k = it * 128 + lane * 2;
        float2 xv[4];
        #pragma unroll
        for (int m = 0; m < 4; ++m)
            xv[m] = *(const float2*)&x[(imgB + m) * 3200 + k];
        #pragma unroll
        for (int o = 0; o < 8; ++o) {
            float2 wvv = *(const float2*)&w[(ocW + o) * 3200 + k];
            #pragma unroll
            for (int m = 0; m < 4; ++m) {
                acc[o][m] = fmaf(wvv.x, xv[m].x, acc[o][m]);
                acc[o][m] = fmaf(wvv.y, xv[m].y, acc[o][m]);
            }
        }
    }
    #pragma unroll
    for (int o = 0; o < 8; ++o)
        #pragma unroll
        for (int m = 0; m < 4; ++m)
            Ls[wv][o * 4 + m][lane] = acc[o][m];
    __syncthreads();

    if (tid < 128) {
        int w2 = tid >> 5, r = tid & 31;
        const float* p = Ls[w2][r];
        float s = 0.f;
        #pragma unroll
        for (int c = 0; c < 64; ++c) s += p[c];
        int o = r >> 2, m = r & 3;
        int oc = ocB + w2 * 8 + o;
        y[(imgB + m) * 128 + oc] = fmaxf(s + bias[oc], 0.f);
    }
}

// ---------------------------------------------------------------------------
// fused fc2+relu, fc3+relu, fc4+log_softmax.
// ---------------------------------------------------------------------------
__global__ __launch_bounds__(64) void k_fc_tail(const float* __restrict__ x,
                                                const float* __restrict__ w2,
                                                const float* __restrict__ b2,
                                                const float* __restrict__ w3,
                                                const float* __restrict__ b3,
                                                const float* __restrict__ w4,
                                                const float* __restrict__ b4,
                                                float* __restrict__ out) {
    __shared__ float xs[128], h2[64], h3[16];
    int img = blockIdx.x;
    int lane = threadIdx.x;

    *(float2*)&xs[lane * 2] = *(const float2*)&x[img * 128 + lane * 2];
    __syncthreads();

    float a = b2[lane];
    const float4* wp = (const float4*)&w2[lane * 128];
    const float4* xp = (const float4*)xs;
    #pragma unroll
    for (int k = 0; k < 32; ++k) {
        float4 wv = wp[k], xv = xp[k];
        a = fmaf(wv.x, xv.x, a);
        a = fmaf(wv.y, xv.y, a);
        a = fmaf(wv.z, xv.z, a);
        a = fmaf(wv.w, xv.w, a);
    }
    h2[lane] = fmaxf(a, 0.f);
    __syncthreads();

    if (lane < 16) {
        float a3 = b3[lane];
        const float4* w3p = (const float4*)&w3[lane * 64];
        const float4* h2p = (const float4*)h2;
        #pragma unroll
        for (int k = 0; k < 16; ++k) {
            float4 wv = w3p[k], xv = h2p[k];
            a3 = fmaf(wv.x, xv.x, a3);
            a3 = fmaf(wv.y, xv.y, a3);
            a3 = fmaf(wv.z, xv.z, a3);
            a3 = fmaf(wv.w, xv.w, a3);
        }
        h3[lane] = fmaxf(a3, 0.f);
    }
    __syncthreads();

    if (lane == 0) {
        float z0 = b4[0], z1 = b4[1];
        #pragma unroll
        for (int k = 0; k < 16; ++k) {
            z0 = fmaf(w4[k],      h3[k], z0);
            z1 = fmaf(w4[16 + k], h3[k], z1);
        }
        float m = fmaxf(z0, z1);
        float lse = m + logf(expf(z0 - m) + expf(z1 - m));
        out[img * 2 + 0] = z0 - lse;
        out[img * 2 + 1] = z1 - lse;
    }
}

// ---------------------------------------------------------------------------
extern "C" void kernel_launch(void* const* d_in, const int* in_sizes, int n_in,
                              void* d_out, int out_size, void* d_ws, size_t ws_size,
                              hipStream_t stream) {
    const float* x       = (const float*)d_in[0];
    const float* conv1_w = (const float*)d_in[1];
    const float* conv1_b = (const float*)d_in[2];
    const float* q_w     = (const float*)d_in[3];
    const float* conv2_w = (const float*)d_in[4];
    const float* conv2_b = (const float*)d_in[5];
    const float* conv3_w = (const float*)d_in[6];
    const float* conv3_b = (const float*)d_in[7];
    const float* conv4_w = (const float*)d_in[8];
    const float* conv4_b = (const float*)d_in[9];
    const float* fc1_w   = (const float*)d_in[10];
    const float* fc1_b   = (const float*)d_in[11];
    const float* fc2_w   = (const float*)d_in[12];
    const float* fc2_b   = (const float*)d_in[13];
    const float* fc3_w   = (const float*)d_in[14];
    const float* fc3_b   = (const float*)d_in[15];
    const float* fc4_w   = (const float*)d_in[16];
    const float* fc4_b   = (const float*)d_in[17];
    float* out = (float*)d_out;

    char* ws = (char*)d_ws;
    float2* V = (float2*)ws;                               // 2 KB
    float* A  = (float*)(ws + 4096);                       // 9.44 MB region
    float* B  = (float*)(ws + 4096 + 9437184);             // 13.2 MB region

    k_build_V<<<1, 256, 0, stream>>>(q_w, V);
    k_conv1t<<<768, 256, 0, stream>>>(x, conv1_w, conv1_b, A);
    k_pool1<<<1936, 256, 0, stream>>>(A, B);
    k_quanv<<<484, 256, 0, stream>>>(B, V, A);
    k_conv2t<<<256, 640, 0, stream>>>(A, conv2_w, conv2_b, B);
    k_pool2<<<8192, 256, 0, stream>>>(B, A);
    k_conv3n<<<256, 416, 0, stream>>>(A, conv3_w, conv3_b, B);
    k_pool3<<<9216, 256, 0, stream>>>(B, A);
    k_conv4p<<<1024, 160, 0, stream>>>(A, conv4_w, B);
    k_c4red<<<3200, 256, 0, stream>>>(B, conv4_b, A);
    k_fc1t<<<256, 256, 0, stream>>>(A, fc1_w, fc1_b, B);
    k_fc_tail<<<256, 64, 0, stream>>>(B, fc2_w, fc2_b, fc3_w, fc3_b,
                                      fc4_w, fc4_b, out);
}

// Round 4
// 192.909 us; speedup vs baseline: 3.6499x; 1.0790x over previous
//
#include <hip/hip_runtime.h>
#include <hip/hip_bf16.h>
#include <math.h>

// ---------------------------------------------------------------------------
// Hybrid_QuanvModel — round 4: conv1 direct (no LDS, float2 loads),
// conv3 oc-split for 2 blocks/CU.
// ---------------------------------------------------------------------------

__device__ __forceinline__ float2 cmul(float2 a, float2 b) {
    return make_float2(a.x * b.x - a.y * b.y, a.x * b.y + a.y * b.x);
}
__device__ __forceinline__ float2 cfma(float2 a, float2 b, float2 acc) {
    acc.x += a.x * b.x - a.y * b.y;
    acc.y += a.x * b.y + a.y * b.x;
    return acc;
}

// ---------------------------------------------------------------------------
// Build V[s][t] = U3[s][t] * (-i)^popcount(t)   (16x16 complex)
// ---------------------------------------------------------------------------
__global__ __launch_bounds__(256) void k_build_V(const float* __restrict__ qw,
                                                 float2* __restrict__ Vout) {
    __shared__ float2 rot[3][4][2][2];
    __shared__ float2 L[16][16];
    __shared__ float2 U[16][16];
    __shared__ float2 T[16][16];

    int tid = threadIdx.x;
    if (tid < 12) {
        int l = tid >> 2, q = tid & 3;
        float phi = qw[(l * 4 + q) * 3 + 0];
        float th  = qw[(l * 4 + q) * 3 + 1];
        float om  = qw[(l * 4 + q) * 3 + 2];
        float c, s;
        sincosf(0.5f * th, &s, &c);
        float sa, ca, sb, cb;
        sincosf(0.5f * (phi + om), &sa, &ca);
        sincosf(0.5f * (phi - om), &sb, &cb);
        rot[l][q][0][0] = make_float2( ca * c, -sa * c);
        rot[l][q][0][1] = make_float2(-cb * s, -sb * s);
        rot[l][q][1][0] = make_float2( cb * s, -sb * s);
        rot[l][q][1][1] = make_float2( ca * c,  sa * c);
    }
    int s = tid >> 4, t = tid & 15;
    U[s][t] = make_float2((s == t) ? 1.f : 0.f, 0.f);
    __syncthreads();

    for (int l = 0; l < 3; ++l) {
        int r = l + 1;
        int ss = s;
        for (int i = 3; i >= 0; --i) {
            int c_ = i, t_ = (i + r) & 3;
            if ((ss >> (3 - c_)) & 1) ss ^= 1 << (3 - t_);
        }
        float2 v = make_float2(1.f, 0.f);
        #pragma unroll
        for (int q = 0; q < 4; ++q) {
            int bs = (ss >> (3 - q)) & 1;
            int bt = (t  >> (3 - q)) & 1;
            v = cmul(v, rot[l][q][bs][bt]);
        }
        L[s][t] = v;
        __syncthreads();
        float2 acc = make_float2(0.f, 0.f);
        #pragma unroll
        for (int k = 0; k < 16; ++k) acc = cfma(L[s][k], U[k][t], acc);
        T[s][t] = acc;
        __syncthreads();
        U[s][t] = T[s][t];
        __syncthreads();
    }
    float2 acc = make_float2(0.f, 0.f);
    #pragma unroll
    for (int k = 0; k < 16; ++k) acc = cfma(U[s][k], U[k][t], acc);
    T[s][t] = acc;
    __syncthreads();
    acc = make_float2(0.f, 0.f);
    #pragma unroll
    for (int k = 0; k < 16; ++k) acc = cfma(T[s][k], U[k][t], acc);
    int pc = __popc(t) & 3;
    float2 v;
    if      (pc == 0) v = acc;
    else if (pc == 1) v = make_float2( acc.y, -acc.x);
    else if (pc == 2) v = make_float2(-acc.x, -acc.y);
    else              v = make_float2(-acc.y,  acc.x);
    Vout[s * 16 + t] = v;
}

// ---------------------------------------------------------------------------
// conv1 (1->1, 8x8, s2) + tanh, direct.  x:(256,186,186) -> y:(256,90,90)
// Thread per output: 32 coalesced float2 loads (L1/L2 reuse) + 64 FMA.
// ---------------------------------------------------------------------------
__global__ __launch_bounds__(256) void k_conv1d(const float* __restrict__ x,
                                                const float* __restrict__ w,
                                                const float* __restrict__ bias,
                                                float* __restrict__ y) {
    int idx = blockIdx.x * 256 + threadIdx.x;      // 256*90*90 = 8100*256 exact
    int j = idx % 90;
    int t = idx / 90;
    int i = t % 90;
    int b = t / 90;
    const float* xb = x + b * 34596 + (2 * i) * 186 + 2 * j;
    float acc = bias[0];
    #pragma unroll
    for (int u = 0; u < 8; ++u) {
        const float* rp = xb + u * 186;
        float2 p0 = *(const float2*)(rp + 0);
        float2 p1 = *(const float2*)(rp + 2);
        float2 p2 = *(const float2*)(rp + 4);
        float2 p3 = *(const float2*)(rp + 6);
        acc = fmaf(w[u * 8 + 0], p0.x, acc);
        acc = fmaf(w[u * 8 + 1], p0.y, acc);
        acc = fmaf(w[u * 8 + 2], p1.x, acc);
        acc = fmaf(w[u * 8 + 3], p1.y, acc);
        acc = fmaf(w[u * 8 + 4], p2.x, acc);
        acc = fmaf(w[u * 8 + 5], p2.y, acc);
        acc = fmaf(w[u * 8 + 6], p3.x, acc);
        acc = fmaf(w[u * 8 + 7], p3.y, acc);
    }
    y[idx] = tanhf(acc);
}

// maxpool 4x4 s2 + *pi/2 : (256,90,90) -> (256,44,44)
__global__ __launch_bounds__(256) void k_pool1(const float* __restrict__ y,
                                               float* __restrict__ p) {
    int idx = blockIdx.x * 256 + threadIdx.x;
    int j = idx % 44;
    int t = idx / 44;
    int i = t % 44;
    int b = t / 44;
    const float* yb = y + b * 8100 + (2 * i) * 90 + 2 * j;
    float m = -INFINITY;
    #pragma unroll
    for (int u = 0; u < 4; ++u)
        #pragma unroll
        for (int v = 0; v < 4; ++v)
            m = fmaxf(m, yb[u * 90 + v]);
    p[idx] = m * 1.57079632679489662f;
}

// ---------------------------------------------------------------------------
// quanv + relu: (256,44,44) -> (256,4,22,22)
// ---------------------------------------------------------------------------
__global__ __launch_bounds__(256) void k_quanv(const float* __restrict__ p,
                                               const float2* __restrict__ Vg,
                                               float* __restrict__ o) {
    __shared__ float2 V[256];
    V[threadIdx.x] = Vg[threadIdx.x];
    __syncthreads();

    int idx = blockIdx.x * 256 + threadIdx.x;
    int j = idx % 22;
    int t = idx / 22;
    int i = t % 22;
    int b = t / 22;
    const float* pb = p + b * 1936 + (2 * i) * 44 + 2 * j;
    float a0 = pb[0], a1 = pb[1], a2 = pb[44], a3 = pb[45];

    float cs[4], sn[4];
    sincosf(0.5f * a0, &sn[0], &cs[0]);
    sincosf(0.5f * a1, &sn[1], &cs[1]);
    sincosf(0.5f * a2, &sn[2], &cs[2]);
    sincosf(0.5f * a3, &sn[3], &cs[3]);

    float c[16];
    #pragma unroll
    for (int tt = 0; tt < 16; ++tt) {
        c[tt] = ((tt & 8) ? sn[0] : cs[0]) * ((tt & 4) ? sn[1] : cs[1]) *
                ((tt & 2) ? sn[2] : cs[2]) * ((tt & 1) ? sn[3] : cs[3]);
    }

    float e0 = 0.f, e1 = 0.f, e2 = 0.f, e3 = 0.f;
    #pragma unroll
    for (int s = 0; s < 16; ++s) {
        float re = 0.f, im = 0.f;
        #pragma unroll
        for (int tt = 0; tt < 16; ++tt) {
            float2 v = V[s * 16 + tt];
            re = fmaf(v.x, c[tt], re);
            im = fmaf(v.y, c[tt], im);
        }
        float pr = re * re + im * im;
        e0 += (s & 8) ? -pr : pr;
        e1 += (s & 4) ? -pr : pr;
        e2 += (s & 2) ? -pr : pr;
        e3 += (s & 1) ? -pr : pr;
    }
    float* ob = o + b * (4 * 484) + i * 22 + j;
    ob[0]    = fmaxf(e0, 0.f);
    ob[484]  = fmaxf(e1, 0.f);
    ob[968]  = fmaxf(e2, 0.f);
    ob[1452] = fmaxf(e3, 0.f);
}

// ---------------------------------------------------------------------------
// conv2 (4->32, 4x4, s1) + relu, LDS tiled. (256,4,22,22) -> (256,32,19,19)
// ---------------------------------------------------------------------------
__global__ __launch_bounds__(640) void k_conv2t(const float* __restrict__ x,
                                                const float* __restrict__ w,
                                                const float* __restrict__ bias,
                                                float* __restrict__ y) {
    __shared__ float Xs[4 * 22 * 28];
    __shared__ float Ws[32 * 68];
    int b = blockIdx.x;
    int tid = threadIdx.x;

    const float* xb = x + b * 1936;
    for (int k = tid; k < 1936; k += 640) {
        int ic = k / 484, rem = k % 484;
        int r = rem / 22, c = rem % 22;
        Xs[ic * 616 + r * 28 + c] = xb[k];
    }
    for (int k = tid; k < 2048; k += 640) {
        Ws[(k >> 6) * 68 + (k & 63)] = w[k];
    }
    __syncthreads();

    if (tid < 608) {
        int oc = tid / 19, i = tid % 19;
        float acc[19];
        float bv = bias[oc];
        #pragma unroll
        for (int j = 0; j < 19; ++j) acc[j] = bv;
        const float* wr = &Ws[oc * 68];
        #pragma unroll
        for (int ic = 0; ic < 4; ++ic) {
            #pragma unroll
            for (int u = 0; u < 4; ++u) {
                const float* rp = &Xs[ic * 616 + (i + u) * 28];
                float xr[22];
                #pragma unroll
                for (int k = 0; k < 5; ++k)
                    *(float4*)&xr[4 * k] = *(const float4*)(rp + 4 * k);
                *(float2*)&xr[20] = *(const float2*)(rp + 20);
                float4 wv = *(const float4*)(wr + ic * 16 + u * 4);
                #pragma unroll
                for (int j = 0; j < 19; ++j) {
                    acc[j] = fmaf(wv.x, xr[j],     acc[j]);
                    acc[j] = fmaf(wv.y, xr[j + 1], acc[j]);
                    acc[j] = fmaf(wv.z, xr[j + 2], acc[j]);
                    acc[j] = fmaf(wv.w, xr[j + 3], acc[j]);
                }
            }
        }
        float* yp = y + b * 11552 + oc * 361 + i * 19;
        #pragma unroll
        for (int j = 0; j < 19; ++j) yp[j] = fmaxf(acc[j], 0.f);
    }
}

// maxpool 4x4 s1: (256,32,19,19) -> (256,32,16,16)
__global__ __launch_bounds__(256) void k_pool2(const float* __restrict__ x,
                                               float* __restrict__ y) {
    int idx = blockIdx.x * 256 + threadIdx.x;
    int j = idx % 16;
    int t = idx / 16;
    int i = t % 16;
    int c = t / 16;
    const float* xb = x + c * 361 + i * 19 + j;
    float m = -INFINITY;
    #pragma unroll
    for (int u = 0; u < 4; ++u)
        #pragma unroll
        for (int v = 0; v < 4; ++v)
            m = fmaxf(m, xb[u * 19 + v]);
    y[idx] = m;
}

// ---------------------------------------------------------------------------
// conv3 (32->64, 4x4, s1) + relu.  (256,32,16,16) -> (256,64,13,13)
// grid = 256 img * 2 oc-halves, block 416 = 32 oc x 13 rows.
// X in LDS (stride 20), W streamed from L2.  2 blocks/CU, 13 waves/CU.
// ---------------------------------------------------------------------------
__global__ __launch_bounds__(416) void k_conv3n(const float* __restrict__ x,
                                                const float* __restrict__ w,
                                                const float* __restrict__ bias,
                                                float* __restrict__ y) {
    __shared__ float Xs[32 * 320];     // [ic][r*20+c], 41 KB
    int bid = blockIdx.x;
    int b = bid >> 1, h = bid & 1;
    int tid = threadIdx.x;

    const float* xb = x + b * 8192;
    for (int k = tid; k < 2048; k += 416) {
        int ic = k >> 6, rem = k & 63;
        int r = rem >> 2, c4 = rem & 3;
        float4 v = *(const float4*)(xb + ic * 256 + r * 16 + c4 * 4);
        *(float4*)(&Xs[ic * 320 + r * 20 + c4 * 4]) = v;
    }
    __syncthreads();

    int oc = tid / 13, i = tid % 13;
    int oca = h * 32 + oc;
    float acc[13];
    float bv = bias[oca];
    #pragma unroll
    for (int j = 0; j < 13; ++j) acc[j] = bv;

    const float* w0 = w + oca * 512;
    for (int ic = 0; ic < 32; ++ic) {
        const float* xc = &Xs[ic * 320 + i * 20];
        #pragma unroll
        for (int u = 0; u < 4; ++u) {
            float xr[16];
            const float* rp = xc + u * 20;
            #pragma unroll
            for (int k = 0; k < 4; ++k)
                *(float4*)&xr[4 * k] = *(const float4*)(rp + 4 * k);
            float4 wa = *(const float4*)(w0 + ic * 16 + u * 4);
            #pragma unroll
            for (int j = 0; j < 13; ++j) {
                acc[j] = fmaf(wa.x, xr[j],     acc[j]);
                acc[j] = fmaf(wa.y, xr[j + 1], acc[j]);
                acc[j] = fmaf(wa.z, xr[j + 2], acc[j]);
                acc[j] = fmaf(wa.w, xr[j + 3], acc[j]);
            }
        }
    }
    float* yp = y + b * 10816 + oca * 169 + i * 13;
    #pragma unroll
    for (int j = 0; j < 13; ++j) yp[j] = fmaxf(acc[j], 0.f);
}

// maxpool 2x2 s1: (256,64,13,13) -> (256,64,12,12)
__global__ __launch_bounds__(256) void k_pool3(const float* __restrict__ x,
                                               float* __restrict__ y) {
    int idx = blockIdx.x * 256 + threadIdx.x;
    int j = idx % 12;
    int t = idx / 12;
    int i = t % 12;
    int c = t / 12;
    const float* xb = x + c * 169 + i * 13 + j;
    float m = fmaxf(fmaxf(xb[0], xb[1]), fmaxf(xb[13], xb[14]));
    y[idx] = m;
}

// ---------------------------------------------------------------------------
// conv4 (64->128, 4x4, s2) partials, K-split-4.
// ---------------------------------------------------------------------------
__global__ __launch_bounds__(160) void k_conv4p(const float* __restrict__ x,
                                                const float* __restrict__ w,
                                                float* __restrict__ part) {
    __shared__ float Xs[2304];         // 16 ic x 144
    int bid = blockIdx.x;
    int b = bid >> 2, kq = bid & 3;
    int ic0 = kq * 16;
    int tid = threadIdx.x;

    const float* xb = x + b * 9216 + ic0 * 144;
    for (int k = tid; k < 576; k += 160)
        *(float4*)&Xs[k * 4] = *(const float4*)(xb + k * 4);
    __syncthreads();

    int ocq = tid / 5, i = tid % 5;
    int oc0 = ocq * 4;
    float acc[4][5];
    #pragma unroll
    for (int o = 0; o < 4; ++o)
        #pragma unroll
        for (int j = 0; j < 5; ++j) acc[o][j] = 0.f;

    const float* wb = w + oc0 * 1024 + ic0 * 16;
    for (int ic = 0; ic < 16; ++ic) {
        const float* xc = &Xs[ic * 144];
        #pragma unroll
        for (int u = 0; u < 4; ++u) {
            const float* rp = xc + (2 * i + u) * 12;
            float xr[12];
            #pragma unroll
            for (int k = 0; k < 3; ++k)
                *(float4*)&xr[4 * k] = *(const float4*)(rp + 4 * k);
            float4 w0 = *(const float4*)(wb +    0 + ic * 16 + u * 4);
            float4 w1 = *(const float4*)(wb + 1024 + ic * 16 + u * 4);
            float4 w2 = *(const float4*)(wb + 2048 + ic * 16 + u * 4);
            float4 w3 = *(const float4*)(wb + 3072 + ic * 16 + u * 4);
            #pragma unroll
            for (int j = 0; j < 5; ++j) {
                float x0 = xr[2 * j], x1 = xr[2 * j + 1];
                float x2 = xr[2 * j + 2], x3 = xr[2 * j + 3];
                acc[0][j] = fmaf(w0.x, x0, acc[0][j]);
                acc[0][j] = fmaf(w0.y, x1, acc[0][j]);
                acc[0][j] = fmaf(w0.z, x2, acc[0][j]);
                acc[0][j] = fmaf(w0.w, x3, acc[0][j]);
                acc[1][j] = fmaf(w1.x, x0, acc[1][j]);
                acc[1][j] = fmaf(w1.y, x1, acc[1][j]);
                acc[1][j] = fmaf(w1.z, x2, acc[1][j]);
                acc[1][j] = fmaf(w1.w, x3, acc[1][j]);
                acc[2][j] = fmaf(w2.x, x0, acc[2][j]);
                acc[2][j] = fmaf(w2.y, x1, acc[2][j]);
                acc[2][j] = fmaf(w2.z, x2, acc[2][j]);
                acc[2][j] = fmaf(w2.w, x3, acc[2][j]);
                acc[3][j] = fmaf(w3.x, x0, acc[3][j]);
                acc[3][j] = fmaf(w3.y, x1, acc[3][j]);
                acc[3][j] = fmaf(w3.z, x2, acc[3][j]);
                acc[3][j] = fmaf(w3.w, x3, acc[3][j]);
            }
        }
    }
    float* pp = part + kq * 819200 + b * 3200 + oc0 * 25 + i * 5;
    #pragma unroll
    for (int o = 0; o < 4; ++o)
        #pragma unroll
        for (int j = 0; j < 5; ++j) pp[o * 25 + j] = acc[o][j];
}

// reduce 4 K-partials + bias + relu -> conv4 out (256,128,5,5)
__global__ __launch_bounds__(256) void k_c4red(const float* __restrict__ part,
                                               const float* __restrict__ bias,
                                               float* __restrict__ y) {
    int idx = blockIdx.x * 256 + threadIdx.x;       // 819200 exact
    float s = part[idx] + part[idx + 819200] + part[idx + 1638400]
            + part[idx + 2457600];
    int oc = (idx / 25) & 127;
    y[idx] = fmaxf(s + bias[oc], 0.f);
}

// ---------------------------------------------------------------------------
// fc1: (256,3200) @ (128,3200)^T + relu.
// ---------------------------------------------------------------------------
__global__ __launch_bounds__(256) void k_fc1t(const float* __restrict__ x,
                                              const float* __restrict__ w,
                                              const float* __restrict__ bias,
                                              float* __restrict__ y) {
    __shared__ float Ls[4][32][65];
    int bid = blockIdx.x;
    int ig = bid >> 2, ocg = bid & 3;
    int imgB = ig * 4, ocB = ocg * 32;
    int tid = threadIdx.x, lane = tid & 63, wv = tid >> 6;
    int ocW = ocB + wv * 8;

    float acc[8][4];
    #pragma unroll
    for (int o = 0; o < 8; ++o)
        #pragma unroll
        for (int m = 0; m < 4; ++m) acc[o][m] = 0.f;

    for (int it = 0; it < 25; ++it) {
        int k = it * 128 + lane * 2;
        float2 xv[4];
        #pragma unroll
        for (int m = 0; m < 4; ++m)
            xv[m] = *(const float2*)&x[(imgB + m) * 3200 + k];
        #pragma unroll
        for (int o = 0; o < 8; ++o) {
            float2 wvv = *(const float2*)&w[(ocW + o) * 3200 + k];
            #pragma unroll
            for (int m = 0; m < 4; ++m) {
                acc[o][m] = fmaf(wvv.x, xv[m].x, acc[o][m]);
                acc[o][m] = fmaf(wvv.y, xv[m].y, acc[o][m]);
            }
        }
    }
    #pragma unroll
    for (int o = 0; o < 8; ++o)
        #pragma unroll
        for (int m = 0; m < 4; ++m)
            Ls[wv][o * 4 + m][lane] = acc[o][m];
    __syncthreads();

    if (tid < 128) {
        int w2 = tid >> 5, r = tid & 31;
        const float* p = Ls[w2][r];
        float s = 0.f;
        #pragma unroll
        for (int c = 0; c < 64; ++c) s += p[c];
        int o = r >> 2, m = r & 3;
        int oc = ocB + w2 * 8 + o;
        y[(imgB + m) * 128 + oc] = fmaxf(s + bias[oc], 0.f);
    }
}

// ---------------------------------------------------------------------------
// fused fc2+relu, fc3+relu, fc4+log_softmax.
// ---------------------------------------------------------------------------
__global__ __launch_bounds__(64) void k_fc_tail(const float* __restrict__ x,
                                                const float* __restrict__ w2,
                                                const float* __restrict__ b2,
                                                const float* __restrict__ w3,
                                                const float* __restrict__ b3,
                                                const float* __restrict__ w4,
                                                const float* __restrict__ b4,
                                                float* __restrict__ out) {
    __shared__ float xs[128], h2[64], h3[16];
    int img = blockIdx.x;
    int lane = threadIdx.x;

    *(float2*)&xs[lane * 2] = *(const float2*)&x[img * 128 + lane * 2];
    __syncthreads();

    float a = b2[lane];
    const float4* wp = (const float4*)&w2[lane * 128];
    const float4* xp = (const float4*)xs;
    #pragma unroll
    for (int k = 0; k < 32; ++k) {
        float4 wv = wp[k], xv = xp[k];
        a = fmaf(wv.x, xv.x, a);
        a = fmaf(wv.y, xv.y, a);
        a = fmaf(wv.z, xv.z, a);
        a = fmaf(wv.w, xv.w, a);
    }
    h2[lane] = fmaxf(a, 0.f);
    __syncthreads();

    if (lane < 16) {
        float a3 = b3[lane];
        const float4* w3p = (const float4*)&w3[lane * 64];
        const float4* h2p = (const float4*)h2;
        #pragma unroll
        for (int k = 0; k < 16; ++k) {
            float4 wv = w3p[k], xv = h2p[k];
            a3 = fmaf(wv.x, xv.x, a3);
            a3 = fmaf(wv.y, xv.y, a3);
            a3 = fmaf(wv.z, xv.z, a3);
            a3 = fmaf(wv.w, xv.w, a3);
        }
        h3[lane] = fmaxf(a3, 0.f);
    }
    __syncthreads();

    if (lane == 0) {
        float z0 = b4[0], z1 = b4[1];
        #pragma unroll
        for (int k = 0; k < 16; ++k) {
            z0 = fmaf(w4[k],      h3[k], z0);
            z1 = fmaf(w4[16 + k], h3[k], z1);
        }
        float m = fmaxf(z0, z1);
        float lse = m + logf(expf(z0 - m) + expf(z1 - m));
        out[img * 2 + 0] = z0 - lse;
        out[img * 2 + 1] = z1 - lse;
    }
}

// ---------------------------------------------------------------------------
extern "C" void kernel_launch(void* const* d_in, const int* in_sizes, int n_in,
                              void* d_out, int out_size, void* d_ws, size_t ws_size,
                              hipStream_t stream) {
    const float* x       = (const float*)d_in[0];
    const float* conv1_w = (const float*)d_in[1];
    const float* conv1_b = (const float*)d_in[2];
    const float* q_w     = (const float*)d_in[3];
    const float* conv2_w = (const float*)d_in[4];
    const float* conv2_b = (const float*)d_in[5];
    const float* conv3_w = (const float*)d_in[6];
    const float* conv3_b = (const float*)d_in[7];
    const float* conv4_w = (const float*)d_in[8];
    const float* conv4_b = (const float*)d_in[9];
    const float* fc1_w   = (const float*)d_in[10];
    const float* fc1_b   = (const float*)d_in[11];
    const float* fc2_w   = (const float*)d_in[12];
    const float* fc2_b   = (const float*)d_in[13];
    const float* fc3_w   = (const float*)d_in[14];
    const float* fc3_b   = (const float*)d_in[15];
    const float* fc4_w   = (const float*)d_in[16];
    const float* fc4_b   = (const float*)d_in[17];
    float* out = (float*)d_out;

    char* ws = (char*)d_ws;
    float2* V = (float2*)ws;                               // 2 KB
    float* A  = (float*)(ws + 4096);                       // 9.44 MB region
    float* B  = (float*)(ws + 4096 + 9437184);             // 13.2 MB region

    k_build_V<<<1, 256, 0, stream>>>(q_w, V);
    k_conv1d<<<8100, 256, 0, stream>>>(x, conv1_w, conv1_b, A);
    k_pool1<<<1936, 256, 0, stream>>>(A, B);
    k_quanv<<<484, 256, 0, stream>>>(B, V, A);
    k_conv2t<<<256, 640, 0, stream>>>(A, conv2_w, conv2_b, B);
    k_pool2<<<8192, 256, 0, stream>>>(B, A);
    k_conv3n<<<512, 416, 0, stream>>>(A, conv3_w, conv3_b, B);
    k_pool3<<<9216, 256, 0, stream>>>(B, A);
    k_conv4p<<<1024, 160, 0, stream>>>(A, conv4_w, B);
    k_c4red<<<3200, 256, 0, stream>>>(B, conv4_b, A);
    k_fc1t<<<256, 256, 0, stream>>>(A, fc1_w, fc1_b, B);
    k_fc_tail<<<256, 64, 0, stream>>>(B, fc2_w, fc2_b, fc3_w, fc3_b,
                                      fc4_w, fc4_b, out);
}